// Round 7
// baseline (113.238 us; speedup 1.0000x reference)
//
#include <hip/hip_runtime.h>

// HBV hydrological model, MI355X (gfx950).
// x (365,1000,3) f32, parameters (365,1000,14,16) f32, staind i32 -> out (365,1000,1) f32.
//
// Latency-bound serial scan (250 waves, 1 wave/CU). R7: NO global loads consumed in
// the main loop. Inputs staged to LDS: x fully up-front; dynamic params (p0,p12) in
// double-buffered 73-step chunks via global_load_lds (dest = uniform base + lane*4).
// Per-step inputs via ds_read (~120cy) covered by a depth-2 register ring. One
// s_waitcnt vmcnt(0) per chunk (j==40); staging row r of chunk k+1 at step r-2 of
// chunk k guarantees a wait between every staging-load and its ds_read.

static constexpr int   NSTEP = 365;
static constexpr int   NGRID = 1000;
static constexpr int   MU    = 16;
static constexpr float PRECS = 1e-5f;
static constexpr int   CHUNK = 73;     // 365 = 5 * 73
static constexpr int   NCH   = 5;

__device__ __forceinline__ float fast_pow(float xx, float yy) {
    return __builtin_amdgcn_exp2f(yy * __builtin_amdgcn_logf(xx));
}

template <int CTRL>
__device__ __forceinline__ float dpp_add(float v) {
    int r = __builtin_amdgcn_update_dpp(0, __float_as_int(v), CTRL, 0xF, 0xF, true);
    return v + __int_as_float(r);
}

// async global->LDS: per-lane global src, LDS dest = uniform base + lane*4
__device__ __forceinline__ void gload_lds(const float* src, float* ldsbase) {
    __builtin_amdgcn_global_load_lds(
        (const __attribute__((address_space(1))) unsigned int*)(const void*)src,
        (__attribute__((address_space(3))) unsigned int*)(void*)ldsbase,
        4, 0, 0);
}

struct In { float P, T, E, p0, p12; };

__global__ __launch_bounds__(64)
void hbv_kernel(const float* __restrict__ x,
                const float* __restrict__ par,
                const int*   __restrict__ staind_p,
                float*       __restrict__ out)
{
    __shared__ float p0buf [2][CHUNK][64];   // 37376 B
    __shared__ float p12buf[2][CHUNK][64];   // 37376 B
    __shared__ float xlds  [4416];           // 17664 B (365*12 used + staging pad)
    __shared__ float qlds  [NSTEP * 4];      //  5840 B

    const int lane  = threadIdx.x;           // 0..63
    const int m     = lane & 15;
    const int gl    = lane >> 4;             // 0..3
    const int gbase = blockIdx.x * 4;
    const int g     = gbase + gl;
    const int staind = *staind_p;

    const size_t tstride = (size_t)NGRID * 14 * MU;
    const int    lp      = g * (14 * MU) + m;     // per-lane param offset within a step

    // ---- static params + derived consts (global loads; waits happen here only) ----
    const float* ps = par + (size_t)staind * tstride + lp;
    const float FC    = 50.0f  + ps[ 1*MU] * (1000.0f - 50.0f);
    const float K0    = 0.05f  + ps[ 2*MU] * (0.9f  - 0.05f);
    const float K1    = 0.01f  + ps[ 3*MU] * (0.5f  - 0.01f);
    const float K2    = 0.001f + ps[ 4*MU] * (0.2f  - 0.001f);
    const float LP    = 0.2f   + ps[ 5*MU] * (1.0f  - 0.2f);
    const float PERCp =          ps[ 6*MU] * 10.0f;
    const float UZL   =          ps[ 7*MU] * 100.0f;
    const float TT    = -2.5f  + ps[ 8*MU] * 5.0f;
    const float CFMAX = 0.5f   + ps[ 9*MU] * (10.0f - 0.5f);
    const float CRF   =          ps[10*MU] * 0.1f * CFMAX;
    const float CWH   =          ps[11*MU] * 0.2f;
    const float C     =          ps[13*MU] * 1.0f;
    const float rFC   = 1.0f / FC;
    const float rLPFC = 1.0f / (LP * FC);

    // ---- state ----
    float SP = 1e-3f, MW = 1e-3f, SM = 1e-3f, SUZ = 1e-3f, SLZ = 1e-3f;

    auto step = [&](int t, const In& in) {
        const float P = in.P, T = in.T, E = in.E;
        const float BETA   = 1.0f + in.p0  * 5.0f;
        const float BETAET = 0.3f + in.p12 * 4.7f;
        const float RAIN = (T >= TT) ? P : 0.0f;
        const float SNOW = P - RAIN;
        const float dT   = T - TT;
        const float acap = fmaxf(CFMAX * dT, 0.0f);
        const float bcap = fmaxf(CRF * (-dT), 0.0f);
        const float SP1  = SP + SNOW;
        const float melt = fminf(acap, SP1);
        const float SP2  = SP1 - melt;
        const float MW1  = MW + melt;
        const float refr = fminf(bcap, MW1);
        const float MW2  = MW1 - refr;
        const float SP3  = SP2 + refr;
        const float lim  = CWH * SP3;
        const float tosoil = fmaxf(MW2 - lim, 0.0f);
        SP = SP3;
        MW = fminf(MW2, lim);

        const float wet    = fminf(fast_pow(SM * rFC, BETA), 1.0f);
        const float excess = fmaxf(SM - FC, 0.0f);
        const float SM1    = fminf(SM, FC);
        const float evapf  = fminf(fast_pow(SM1 * rLPFC, BETAET), 1.0f);
        const float SM2    = fmaxf(SM1 - E * evapf, PRECS);
        const float rt     = RAIN + tosoil;
        const float recharge = rt * wet;
        const float SM3    = SM2 + rt - recharge;
        const float cap    = fminf(SLZ, C * SLZ * (1.0f - fminf(SM3 * rFC, 1.0f)));
        SM = fmaxf(SM3 + cap, PRECS);
        const float SLZ1   = fmaxf(SLZ - cap, PRECS);

        const float SUZ1 = SUZ + recharge + excess;
        const float PERC = fminf(SUZ1, PERCp);
        const float SUZ2 = SUZ1 - PERC;
        const float Q0   = K0 * fmaxf(SUZ2 - UZL, 0.0f);
        const float SUZ3 = SUZ2 - Q0;
        const float Q1   = K1 * SUZ3;
        SUZ = SUZ3 - Q1;
        const float SLZ2 = SLZ1 + PERC;
        const float Q2   = K2 * SLZ2;
        SLZ = SLZ2 - Q2;

        float Q = Q0 + Q1 + Q2;
        Q = dpp_add<0xB1>(Q);    // xor 1
        Q = dpp_add<0x4E>(Q);    // xor 2
        Q = dpp_add<0x141>(Q);   // row_half_mirror
        Q = dpp_add<0x140>(Q);   // row_mirror -> 16-lane sum
        qlds[t * 4 + gl] = Q * 0.0625f;
    };

    // ds_read one input row: params from buf b row r, x from step t
    auto ldrow = [&](int b, int r, int t) -> In {
        In v;
        v.p0  = p0buf [b][r][lane];
        v.p12 = p12buf[b][r][lane];
        const int xb = t * 12 + gl * 3;
        v.P = xlds[xb + 0];
        v.T = xlds[xb + 1];
        v.E = xlds[xb + 2];
        return v;
    };

    // ---- prologue: stage chunk 0 params (73 rows) + ALL x ----
    const float* sp = par + lp;              // advances tstride per staged row
#pragma unroll 1
    for (int r = 0; r < CHUNK; ++r) {
        gload_lds(sp,       &p0buf [0][r][0]);
        gload_lds(sp + 192, &p12buf[0][r][0]);   // i=12 plane: +192 elems (768 B)
        sp += tstride;
    }
    // x: 365*12 = 4380 floats, 69 wave-loads; i = it*64+lane; t = i/12 via mul-shift
#pragma unroll 1
    for (int it = 0; it < 69; ++it) {
        const int i = it * 64 + lane;
        int t = (int)(((unsigned)i * 21846u) >> 18);   // i/12 exact for i < 262k/12
        t = min(t, 364);                                // tail lanes: clamp (dest dead)
        const int k = i - t * 12;
        gload_lds(x + (size_t)t * (NGRID * 3) + gbase * 3 + k, &xlds[it * 64]);
    }
    asm volatile("s_waitcnt vmcnt(0)" ::: "memory");

    In c = ldrow(0, 0, 0);
    In n = ldrow(0, 1, 1);
    int bcur = 0;

    // sp now points at chunk 1 row 0; it advances monotonically through all staging.
    for (int ch = 0; ch < NCH; ++ch) {
        const int  t0 = ch * CHUNK;
        const bool st = (ch < NCH - 1);
        const int  bn = bcur ^ 1;

        // stage next-chunk rows 0,1 (read at this chunk's peeled steps 71,72;
        // the j==40 wait sits in between)
        if (st) {
            gload_lds(sp,       &p0buf [bn][0][0]);
            gload_lds(sp + 192, &p12buf[bn][0][0]);
            sp += tstride;
            gload_lds(sp,       &p0buf [bn][1][0]);
            gload_lds(sp + 192, &p12buf[bn][1][0]);
            sp += tstride;
        }

#pragma unroll 1
        for (int j = 0; j < 71; ++j) {
            // prefetch inputs for step t0+j+2 (consumed 2 steps later, ~120cy LDS)
            In tp = ldrow(bcur, j + 2, t0 + j + 2);
            // stage next-chunk row j+2 (ds_read of it is separated by a vmcnt(0):
            // rows r-2<=40 by THIS chunk's j==40 wait, rows r-2>40 by the NEXT one)
            if (st) {
                gload_lds(sp,       &p0buf [bn][j + 2][0]);
                gload_lds(sp + 192, &p12buf[bn][j + 2][0]);
                sp += tstride;
            }
            if (j == 40) asm volatile("s_waitcnt vmcnt(0)" ::: "memory");
            step(t0 + j, c);
            c = n; n = tp;
        }
        // peeled j=71,72: prefetch rows 0,1 of the next buffer
        {
            const int tn0 = st ? (t0 + CHUNK) : t0;   // last chunk: dead reads, in-bounds
            In tp = ldrow(bn, 0, tn0);
            step(t0 + 71, c);
            c = n; n = tp;
            In tp2 = ldrow(bn, 1, tn0 + 1);
            step(t0 + 72, c);
            c = n; n = tp2;
        }
        bcur = bn;
    }

    // ---- flush: LDS -> global, coalesced (1 wave/block, no barrier needed) ----
    for (int i = lane; i < NSTEP * 4; i += 64) {
        out[(i >> 2) * NGRID + gbase + (i & 3)] = qlds[i];
    }
}

extern "C" void kernel_launch(void* const* d_in, const int* in_sizes, int n_in,
                              void* d_out, int out_size, void* d_ws, size_t ws_size,
                              hipStream_t stream) {
    const float* x      = (const float*)d_in[0];
    const float* par    = (const float*)d_in[1];
    const int*   staind = (const int*)d_in[2];
    float*       out    = (float*)d_out;

    hipLaunchKernelGGL(hbv_kernel, dim3(NGRID / 4), dim3(64), 0, stream,
                       x, par, staind, out);
}

// Round 8
// 62.744 us; speedup vs baseline: 1.8048x; 1.8048x over previous
//
#include <hip/hip_runtime.h>

// HBV hydrological model, MI355X (gfx950).
// x (365,1000,3) f32, parameters (365,1000,14,16) f32, staind i32 -> out (365,1000,1) f32.
//
// Latency-bound serial scan (250 waves, 1 wave/CU). Working model: per-step time ~
// op_count x (issue+dep latency) -- scheduler emits near source order. So: minimize
// ops on the chain.
// R8: single-log pow algebra (1 v_log/step; exp2-clamp identity min(exp2(z),1)=
// exp2(min(z,0)); log2(min(SM,FC))=min(lg,lgFC)) + deferred mu-reduction (per-lane Q
// to LDS, 16-sum in final flush -- deletes 4 DPP + mul per step).
// Carried from R4: depth-10 register ring, no global ops in loop except ring refills,
// LDS-staged output, coalesced flush.

static constexpr int   NSTEP = 365;
static constexpr int   NGRID = 1000;
static constexpr int   MU    = 16;
static constexpr float PRECS = 1e-5f;
static constexpr int   DEPTH = 10;
static constexpr int   QPAD  = 68;     // qlds row stride (words): 64 + 4 pad

__global__ __launch_bounds__(64)
void hbv_kernel(const float* __restrict__ x,
                const float* __restrict__ par,
                const int*   __restrict__ staind_p,
                float*       __restrict__ out)
{
    __shared__ float qlds[NSTEP * QPAD];   // 99,280 B: per-lane Q per step

    const int lane = threadIdx.x;          // 0..63
    const int m    = lane & 15;            // mu index
    const int gl   = lane >> 4;            // 0..3 local g
    const int gbase = blockIdx.x * 4;
    const int g    = gbase + gl;
    const int staind = *staind_p;

    const size_t tstride = (size_t)NGRID * 14 * MU;
    const int    xstride = NGRID * 3;

    // ---- static params: parameters[staind, g, i, m] ----
    const float* ps = par + (size_t)staind * tstride + (size_t)g * 14 * MU + m;
    const float FC    = 50.0f  + ps[ 1*MU] * (1000.0f - 50.0f);
    const float K0    = 0.05f  + ps[ 2*MU] * (0.9f  - 0.05f);
    const float K1    = 0.01f  + ps[ 3*MU] * (0.5f  - 0.01f);
    const float K2    = 0.001f + ps[ 4*MU] * (0.2f  - 0.001f);
    const float LP    = 0.2f   + ps[ 5*MU] * (1.0f  - 0.2f);
    const float PERCp =          ps[ 6*MU] * 10.0f;
    const float UZL   =          ps[ 7*MU] * 100.0f;
    const float TT    = -2.5f  + ps[ 8*MU] * 5.0f;
    const float CFMAX = 0.5f   + ps[ 9*MU] * (10.0f - 0.5f);
    const float CRF   =          ps[10*MU] * 0.1f * CFMAX;
    const float CWH   =          ps[11*MU] * 0.2f;
    const float C     =          ps[13*MU] * 1.0f;
    const float rFC   = 1.0f / FC;
    // log-domain constants (same v_log instruction as in-loop -> exact identity
    // log2(min(SM,FC)) == min(log2(SM), lgFC))
    const float lgFC   = __builtin_amdgcn_logf(FC);
    const float lgLPFC = __builtin_amdgcn_logf(LP * FC);

    // ---- state ----
    float SP = 1e-3f, MW = 1e-3f, SM = 1e-3f, SUZ = 1e-3f, SLZ = 1e-3f;

    auto step = [&](int t, float P, float T, float E, float p0, float p12) {
        // off-chain prep (depends only on ring inputs)
        const float BETA    = 1.0f + p0  * 5.0f;
        const float BETAET  = 0.3f + p12 * 4.7f;
        const float nBlgFC  = -BETA   * lgFC;
        const float nBElgLP = -BETAET * lgLPFC;
        const float RAIN = (T >= TT) ? P : 0.0f;
        const float SNOW = P - RAIN;                       // exact split
        const float dT   = T - TT;
        const float acap = fmaxf(CFMAX * dT, 0.0f);
        const float bcap = fmaxf(CRF * (-dT), 0.0f);

        // snow module (SP, MW)
        const float SP1  = SP + SNOW;
        const float melt = fminf(acap, SP1);
        const float SP2  = SP1 - melt;
        const float MW1  = MW + melt;
        const float refr = fminf(bcap, MW1);
        const float MW2  = MW1 - refr;
        const float SP3  = SP2 + refr;
        const float lim  = CWH * SP3;
        const float tosoil = fmaxf(MW2 - lim, 0.0f);
        SP = SP3;
        MW = fminf(MW2, lim);                              // MW2 - tosoil (exact)

        // soil module -- single-log form
        const float lg    = __builtin_amdgcn_logf(SM);     // log2(SM), SM >= PRECS
        const float wet   = __builtin_amdgcn_exp2f(fminf(fmaf(BETA, lg, nBlgFC), 0.0f));
        const float excess = fmaxf(SM - FC, 0.0f);
        const float SM1   = fminf(SM, FC);                 // SM - excess (exact)
        const float lg1   = fminf(lg, lgFC);               // log2(SM1) (exact)
        const float evapf = __builtin_amdgcn_exp2f(fminf(fmaf(BETAET, lg1, nBElgLP), 0.0f));
        const float SM2   = fmaxf(fmaf(-E, evapf, SM1), PRECS);   // ETact fold (exact)
        const float rt    = RAIN + tosoil;
        const float recharge = rt * wet;
        const float SM3   = SM2 + rt - recharge;
        const float capf  = fmaxf(fmaf(-SM3, rFC, 1.0f), 0.0f);   // 1-min(s,1)=max(1-s,0)
        const float cap   = fminf(SLZ, (C * SLZ) * capf);
        SM = fmaxf(SM3 + cap, PRECS);
        const float SLZ1  = fmaxf(SLZ - cap, PRECS);

        // response
        const float SUZ1 = SUZ + recharge + excess;
        const float PERC = fminf(SUZ1, PERCp);
        const float SUZ2 = SUZ1 - PERC;
        const float Q0   = K0 * fmaxf(SUZ2 - UZL, 0.0f);
        const float SUZ3 = SUZ2 - Q0;
        const float Q1   = K1 * SUZ3;
        SUZ = SUZ3 - Q1;
        const float SLZ2 = SLZ1 + PERC;
        const float Q2   = K2 * SLZ2;
        SLZ = SLZ2 - Q2;

        // per-lane Q to LDS; mu-reduction deferred to the flush
        qlds[t * QPAD + lane] = Q0 + Q1 + Q2;
    };

    // ---- depth-10 register ring ----
    const float* pd = par + (size_t)g * 14 * MU + m;
    const float* xp = x   + (size_t)g * 3;

    float bP[DEPTH], bT[DEPTH], bE[DEPTH], b0[DEPTH], b12[DEPTH];
    const float* pdp = pd;
    const float* xpp = xp;
#pragma unroll
    for (int j = 0; j < DEPTH; ++j) {      // slots 0..9 = steps 0..9
        b0[j]  = pdp[0];
        b12[j] = pdp[12*MU];
        bP[j]  = xpp[0];
        bT[j]  = xpp[1];
        bE[j]  = xpp[2];
        pdp += tstride;
        xpp += xstride;
    }

    // main: steps 0..349, refills steps 10..359 -- unconditional advance
    for (int tb = 0; tb < 350; tb += DEPTH) {
#pragma unroll
        for (int j = 0; j < DEPTH; ++j) {
            const float P = bP[j], T = bT[j], E = bE[j], p0 = b0[j], p12 = b12[j];
            b0[j]  = pdp[0];
            b12[j] = pdp[12*MU];
            bP[j]  = xpp[0];
            bT[j]  = xpp[1];
            bE[j]  = xpp[2];
            pdp += tstride;
            xpp += xstride;
            step(tb + j, P, T, E, p0, p12);
        }
    }

    // peeled block: steps 350..359, refill rows 360..364 then stop advancing
#pragma unroll
    for (int j = 0; j < DEPTH; ++j) {
        const float P = bP[j], T = bT[j], E = bE[j], p0 = b0[j], p12 = b12[j];
        b0[j]  = pdp[0];
        b12[j] = pdp[12*MU];
        bP[j]  = xpp[0];
        bT[j]  = xpp[1];
        bE[j]  = xpp[2];
        if (j < 4) { pdp += tstride; xpp += xstride; }   // stop at row 364
        step(350 + j, P, T, E, p0, p12);
    }

    // epilogue: steps 360..364 from slots 0..4
#pragma unroll
    for (int j = 0; j < 5; ++j)
        step(360 + j, bP[j], bT[j], bE[j], b0[j], b12[j]);

    // ---- flush: 16-lane sums + coalesced global stores (1 wave/block, no barrier;
    //      compiler inserts the lgkmcnt wait before the LDS reads) ----
    for (int i = lane; i < NSTEP * 4; i += 64) {
        const int t  = i >> 2;
        const int gg = i & 3;
        const float* row = &qlds[t * QPAD + gg * 16];
        float s = 0.0f;
#pragma unroll
        for (int k = 0; k < 16; ++k) s += row[k];
        out[t * NGRID + gbase + gg] = s * 0.0625f;
    }
}

extern "C" void kernel_launch(void* const* d_in, const int* in_sizes, int n_in,
                              void* d_out, int out_size, void* d_ws, size_t ws_size,
                              hipStream_t stream) {
    const float* x      = (const float*)d_in[0];
    const float* par    = (const float*)d_in[1];
    const int*   staind = (const int*)d_in[2];
    float*       out    = (float*)d_out;

    hipLaunchKernelGGL(hbv_kernel, dim3(NGRID / 4), dim3(64), 0, stream,
                       x, par, staind, out);
}